// Round 3
// baseline (41.983 us; speedup 1.0000x reference)
//
#include <hip/hip_runtime.h>

// 512*512 letters of 16x8 fp32; 3x3 VALID conv -> 14x6 = 84 outputs per letter.
// Barrier-free version: each wave is an independent load->compute->store pipeline.
typedef float f4 __attribute__((ext_vector_type(4)));

#define BLOCK 256
#define LPW 16                            // letters per wave
#define LETTER_SZ 128                     // floats per letter
#define IN_FLOATS_W (LPW * LETTER_SZ)     // 2048 floats = 8 KB LDS slab per wave
#define OPL 84                            // outputs per letter
#define OUT_FLOATS_W (LPW * OPL)          // 1344 floats (fits in the 2048 slab)
#define LETTERS_PER_BLOCK (4 * LPW)       // 64

__global__ __launch_bounds__(BLOCK) void conv_letters_kernel(
    const float* __restrict__ x,
    const float* __restrict__ kern,
    float* __restrict__ out)
{
    __shared__ float s[4 * IN_FLOATS_W];  // 32 KB -> 5 blocks/CU, 20 waves/CU

    const int t = threadIdx.x;
    const int w = t >> 6;
    const int lane = t & 63;
    float* slab = s + w * IN_FLOATS_W;    // this wave's private slab

    const long long l0 = (long long)blockIdx.x * LETTERS_PER_BLOCK + w * LPW;

    // ---- Phase 1: coalesced f4 NT loads of this wave's 16 letters into LDS.
    const f4* in4 = reinterpret_cast<const f4*>(x) + l0 * (LETTER_SZ / 4);
    #pragma unroll
    for (int i = 0; i < IN_FLOATS_W / 4 / 64; ++i) {   // 8 iters
        const int j = lane + i * 64;
        *reinterpret_cast<f4*>(slab + 4 * j) = __builtin_nontemporal_load(in4 + j);
    }

    const float k0 = kern[0], k1 = kern[1], k2 = kern[2];
    const float k3 = kern[3], k4 = kern[4], k5 = kern[5];
    const float k6 = kern[6], k7 = kern[7], k8 = kern[8];

    // Wave-local ordering: all this wave's ds_writes complete before its reads.
    asm volatile("s_waitcnt lgkmcnt(0)" ::: "memory");
    __builtin_amdgcn_sched_barrier(0);

    // ---- Phase 2: 21 outputs per lane, accumulated in registers (static idx).
    float acc[21];
    #pragma unroll
    for (int i = 0; i < 21; ++i) {
        const int oidx   = lane + i * 64;           // 0..1343 within wave
        const int letter = oidx / OPL;
        const int within = oidx - letter * OPL;
        const int ho     = within / 6;
        const int wo     = within - ho * 6;
        const float* p = slab + letter * LETTER_SZ + ho * 8 + wo;
        acc[i] = k0 * p[0]  + k1 * p[1]  + k2 * p[2]
               + k3 * p[8]  + k4 * p[9]  + k5 * p[10]
               + k6 * p[16] + k7 * p[17] + k8 * p[18];
    }

    // All input reads complete before the slab is reused for output staging.
    asm volatile("s_waitcnt lgkmcnt(0)" ::: "memory");
    __builtin_amdgcn_sched_barrier(0);

    #pragma unroll
    for (int i = 0; i < 21; ++i)
        slab[lane + i * 64] = acc[i];

    asm volatile("s_waitcnt lgkmcnt(0)" ::: "memory");
    __builtin_amdgcn_sched_barrier(0);

    // ---- Phase 3: coalesced f4 NT stores (336 f4 per wave = 5*64 + 16).
    f4* ob = reinterpret_cast<f4*>(out + l0 * OPL);
    const f4* so4 = reinterpret_cast<const f4*>(slab);
    #pragma unroll
    for (int i = 0; i < 5; ++i)
        __builtin_nontemporal_store(so4[lane + i * 64], ob + lane + i * 64);
    if (lane < 16)
        __builtin_nontemporal_store(so4[lane + 320], ob + lane + 320);
}

extern "C" void kernel_launch(void* const* d_in, const int* in_sizes, int n_in,
                              void* d_out, int out_size, void* d_ws, size_t ws_size,
                              hipStream_t stream) {
    const float* x    = (const float*)d_in[0];   // (512,512,128) fp32
    const float* kern = (const float*)d_in[1];   // (3,3) fp32
    float* out = (float*)d_out;                  // (1,512,512,84) fp32

    const int total_letters = in_sizes[0] / LETTER_SZ;      // 262144
    const int grid = total_letters / LETTERS_PER_BLOCK;      // 4096

    conv_letters_kernel<<<grid, BLOCK, 0, stream>>>(x, kern, out);
}

// Round 4
// 41.421 us; speedup vs baseline: 1.0136x; 1.0136x over previous
//
#include <hip/hip_runtime.h>

// 512*512 letters of 16x8 fp32; 3x3 VALID conv -> 14x6 = 84 outputs per letter.
// Software-pipelined version: global_load_lds DMA, double-buffered wave-private
// slabs, counted vmcnt waits (never drain to 0 mid-loop), stores from registers.

#define BLOCK 256
#define LPW 16                             // letters per slab
#define LETTER_SZ 128                      // floats per letter
#define SLAB_FLOATS (LPW * LETTER_SZ)      // 2048 floats = 8 KB
#define OPL 84
#define OUT_PER_SLAB (LPW * OPL)           // 1344 floats
#define SLABS_PER_WAVE 8

__device__ __forceinline__ void dma16(const float* g, float* l) {
    // gptr per-lane; LDS dest = wave-uniform base + lane*16B (m104 semantics)
    __builtin_amdgcn_global_load_lds(
        (const __attribute__((address_space(1))) void*)g,
        (__attribute__((address_space(3))) void*)l, 16, 0, 0);
}

__global__ __launch_bounds__(BLOCK) void conv_letters_kernel(
    const float* __restrict__ x,
    const float* __restrict__ kern,
    float* __restrict__ out)
{
    __shared__ float s[4 * 2 * SLAB_FLOATS];   // 64 KB: 4 waves x 2 slabs

    const int t = threadIdx.x;
    const int w = t >> 6;
    const int lane = t & 63;
    float* lds = s + w * 2 * SLAB_FLOATS;      // this wave's double buffer

    const int wid = blockIdx.x * 4 + w;        // 0..2047
    const float* gbase = x + (size_t)wid * SLABS_PER_WAVE * SLAB_FLOATS;
    float* obase = out + (size_t)wid * SLABS_PER_WAVE * OUT_PER_SLAB;

    const float k0 = kern[0], k1 = kern[1], k2 = kern[2];
    const float k3 = kern[3], k4 = kern[4], k5 = kern[5];
    const float k6 = kern[6], k7 = kern[7], k8 = kern[8];

    // Prologue: DMA slab 0 (8 x 1KB wave-instructions)
    #pragma unroll
    for (int i = 0; i < 8; ++i)
        dma16(gbase + (size_t)(i * 64 + lane) * 4, lds + i * 256);

    #pragma unroll 1
    for (int k = 0; k < SLABS_PER_WAVE; ++k) {
        const float* cur = lds + (k & 1) * SLAB_FLOATS;

        // Issue next slab's DMA before waiting on the current one.
        if (k + 1 < SLABS_PER_WAVE) {
            const float* gn = gbase + (size_t)(k + 1) * SLAB_FLOATS;
            float* nxt = lds + ((k + 1) & 1) * SLAB_FLOATS;
            #pragma unroll
            for (int i = 0; i < 8; ++i)
                dma16(gn + (size_t)(i * 64 + lane) * 4, nxt + i * 256);
        }

        // Counted waits: exact FIFO arithmetic (DMA=8/slab, stores=21/slab).
        // k==0:  queue = [DMA0:8][DMA1:8]            -> vmcnt(8)  retires DMA0
        // mid:   queue = [DMAk:8][st(k-1):21][DMA(k+1):8] -> vmcnt(29) retires DMAk
        // last:  queue = [DMAk:8][st(k-1):21]        -> vmcnt(21) retires DMAk
        if (k == 0)                         { asm volatile("s_waitcnt vmcnt(8)"  ::: "memory"); }
        else if (k + 1 < SLABS_PER_WAVE)    { asm volatile("s_waitcnt vmcnt(29)" ::: "memory"); }
        else                                { asm volatile("s_waitcnt vmcnt(21)" ::: "memory"); }
        __builtin_amdgcn_sched_barrier(0);

        // Compute 21 outputs/lane from LDS, store straight from registers
        // (lane-consecutive scalar NT stores = coalesced 256B/instr).
        float* outk = obase + (size_t)k * OUT_PER_SLAB;
        #pragma unroll
        for (int i = 0; i < 21; ++i) {
            const int oidx   = lane + i * 64;            // 0..1343
            const int letter = oidx / OPL;
            const int within = oidx - letter * OPL;
            const int ho     = within / 6;
            const int wo     = within - ho * 6;
            const float* p = cur + letter * LETTER_SZ + ho * 8 + wo;
            const float acc =
                  k0 * p[0]  + k1 * p[1]  + k2 * p[2]
                + k3 * p[8]  + k4 * p[9]  + k5 * p[10]
                + k6 * p[16] + k7 * p[17] + k8 * p[18];
            __builtin_nontemporal_store(acc, outk + oidx);
        }
    }
}

extern "C" void kernel_launch(void* const* d_in, const int* in_sizes, int n_in,
                              void* d_out, int out_size, void* d_ws, size_t ws_size,
                              hipStream_t stream) {
    const float* x    = (const float*)d_in[0];   // (512,512,128) fp32
    const float* kern = (const float*)d_in[1];   // (3,3) fp32
    float* out = (float*)d_out;                  // (1,512,512,84) fp32

    const int total_letters = in_sizes[0] / LETTER_SZ;              // 262144
    const int grid = total_letters / (LPW * SLABS_PER_WAVE * 4);     // 512

    conv_letters_kernel<<<grid, BLOCK, 0, stream>>>(x, kern, out);
}